// Round 4
// baseline (464.609 us; speedup 1.0000x reference)
//
#include <hip/hip_runtime.h>

#define H 512
#define NNODES 10000
#define NEDGES 160000
#define NLAYERS 5

typedef __attribute__((ext_vector_type(8))) short short8;
typedef __attribute__((ext_vector_type(16))) float floatx16;

// ---------- helpers ----------
__device__ inline unsigned short f2bf(float v) {
    union { float f; unsigned int u; } x; x.f = v;
    unsigned int r = (x.u + 0x7fffu + ((x.u >> 16) & 1u)) >> 16;
    return (unsigned short)r;
}
__device__ inline float bf2f(unsigned short u) {
    union { unsigned int u; float f; } x; x.u = ((unsigned int)u) << 16; return x.f;
}
__device__ inline void gl_lds16(const void* g, void* l) {
    __builtin_amdgcn_global_load_lds((const __attribute__((address_space(1))) void*)g,
                                     (__attribute__((address_space(3))) void*)l, 16, 0, 0);
}

// ---------- prep kernels ----------
__global__ void zero_int(int* __restrict__ p, int n) {
    int i = blockIdx.x * blockDim.x + threadIdx.x;
    if (i < n) p[i] = 0;
}

__global__ void cvt_f32_bf16(const float* __restrict__ in, unsigned short* __restrict__ out, int n4) {
    int i = blockIdx.x * blockDim.x + threadIdx.x;
    if (i < n4) {
        float4 v = ((const float4*)in)[i];
        ushort4 o;
        o.x = f2bf(v.x); o.y = f2bf(v.y); o.z = f2bf(v.z); o.w = f2bf(v.w);
        ((ushort4*)out)[i] = o;
    }
}

// batched: z in [0,6): 5 layer weights + vw1. out[n][k] = in[k][n], bf16
__global__ void transpose_cvt6(const float* __restrict__ Wg, const float* __restrict__ vw1,
                               unsigned short* __restrict__ Wt) {
    __shared__ float tile[32][33];
    const int z = blockIdx.z;
    const float* in = (z < NLAYERS) ? (Wg + (size_t)z * H * H) : vw1;
    unsigned short* out = Wt + (size_t)z * H * H;
    const int bx = blockIdx.x * 32;  // n base
    const int by = blockIdx.y * 32;  // k base
    const int tx = threadIdx.x, ty = threadIdx.y;  // (32,8)
    for (int i = ty; i < 32; i += 8)
        tile[i][tx] = in[(size_t)(by + i) * H + bx + tx];
    __syncthreads();
    for (int i = ty; i < 32; i += 8)
        out[(size_t)(bx + i) * H + by + tx] = f2bf(tile[tx][i]);
}

__global__ void edge_hist(const int* __restrict__ rows, int* __restrict__ counts, int n) {
    int i = blockIdx.x * blockDim.x + threadIdx.x;
    if (i < n) atomicAdd(&counts[rows[i]], 1);
}

__global__ __launch_bounds__(1024)
void scan_rows(const int* __restrict__ counts, int* __restrict__ row_ptr, int n) {
    __shared__ int sums[1024];
    const int t = threadIdx.x;
    const int base = t * 16;
    int local[16];
    int s = 0;
#pragma unroll
    for (int i = 0; i < 16; ++i) {
        int idx = base + i;
        int v = (idx < n) ? counts[idx] : 0;
        local[i] = s;
        s += v;
    }
    sums[t] = s;
    __syncthreads();
    for (int off = 1; off < 1024; off <<= 1) {
        int v = (t >= off) ? sums[t - off] : 0;
        __syncthreads();
        sums[t] += v;
        __syncthreads();
    }
    const int prefix = (t == 0) ? 0 : sums[t - 1];
#pragma unroll
    for (int i = 0; i < 16; ++i) {
        int idx = base + i;
        if (idx < n) row_ptr[idx] = prefix + local[i];
    }
    if (t == 0) row_ptr[n] = sums[1023];
}

__global__ void edge_scatter(const int* __restrict__ rows, const int* __restrict__ colsin,
                             const float* __restrict__ valsin, const int* __restrict__ row_ptr,
                             int* __restrict__ fill, int* __restrict__ colsout,
                             float* __restrict__ valsout, int* __restrict__ eidx, int n) {
    int i = blockIdx.x * blockDim.x + threadIdx.x;
    if (i < n) {
        int r = rows[i];
        int pos = row_ptr[r] + atomicAdd(&fill[r], 1);
        colsout[pos] = colsin[i];
        valsout[pos] = valsin[i];
        eidx[pos] = i;
    }
}

// per-row odd-even transposition sort by original edge index -> accumulation
// order matches reference segment_sum exactly (deterministic absmax).
__global__ __launch_bounds__(256)
void sort_rows(const int* __restrict__ row_ptr, int* __restrict__ cols,
               float* __restrict__ vals, const int* __restrict__ eidx) {
    const int wave = threadIdx.x >> 6, lane = threadIdx.x & 63;
    const int r = blockIdx.x * 4 + wave;
    if (r >= NNODES) return;
    const int s = row_ptr[r], e = row_ptr[r + 1];
    const int len = e - s;
    if (len <= 1) return;
    const int n = len < 64 ? len : 64;
    int key = (lane < n) ? eidx[s + lane] : 0x7fffffff;
    int col = (lane < n) ? cols[s + lane] : 0;
    float val = (lane < n) ? vals[s + lane] : 0.f;
    for (int rd = 0; rd < 64; ++rd) {
        const int p = rd & 1;
        const bool up = ((lane & 1) == p);
        int partner = up ? lane + 1 : lane - 1;
        const bool valid = (partner >= 0) && (partner < 64);
        if (!valid) partner = lane;
        int pk = __shfl(key, partner, 64);
        int pc = __shfl(col, partner, 64);
        float pv = __shfl(val, partner, 64);
        if (valid) {
            const bool sw = up ? (pk < key) : (pk > key);
            if (sw) { key = pk; col = pc; val = pv; }
        }
    }
    if (lane < n) { cols[s + lane] = col; vals[s + lane] = val; }
}

// ---------- W-stationary GEMM: C[M,512] = A[M,512] * Bt[512,512]^T (all bf16) ----------
// Block: 64-col W-slice staged ONCE into LDS in MFMA-fragment-major order
// (slot = (nb*32+ks)*64 + lane -> ds_read_b128 lane-contiguous, conflict-free).
// K-loop: ZERO barriers. A frags global->VGPR (16B/lane), double-buffered x8.
// MFMA 32x32x16 (16 FLOP/operand-byte, 2x the 16x16x32 intensity).
// Grid (79, 8) = 632 blocks; 64KB LDS -> 2 blocks/CU, 8 waves/CU.
__global__ __launch_bounds__(256)
void gemm_ws(const unsigned short* __restrict__ A, const unsigned short* __restrict__ Bt,
             unsigned short* __restrict__ C, const float* __restrict__ bias,
             int has_bias_relu, int M) {
    __shared__ __align__(16) unsigned short lsW[64 * 512];  // 64 KB, frag-major
    const int t = threadIdx.x;
    const int lane = t & 63;
    const int wave = t >> 6;        // 0..3
    const int l31 = lane & 31;
    const int khalf = lane >> 5;    // 0/1
    const int tileN = blockIdx.y * 64;
    const int m0 = blockIdx.x * 128 + wave * 32;

    // ---- stage W-slice (frag-major): group p = nb*32 + ks, p in [0,64) ----
#pragma unroll
    for (int i = 0; i < 16; ++i) {
        const int p = wave + 4 * i;
        const int nb = p >> 5, ks = p & 31;
        const unsigned short* src =
            Bt + (size_t)(tileN + nb * 32 + l31) * 512 + ks * 16 + khalf * 8;
        gl_lds16(src, lsW + (size_t)p * 512 + lane * 8);  // = p*1024B + lane*16B
    }
    __syncthreads();  // one-time drain; no barriers after this

    int mrow = m0 + l31; if (mrow >= M) mrow = M - 1;
    const unsigned short* arow = A + (size_t)mrow * 512 + khalf * 8;

    floatx16 acc0 = {}, acc1 = {};
    short8 a[2][8];
#pragma unroll
    for (int ks = 0; ks < 8; ++ks) a[0][ks] = *(const short8*)(arow + ks * 16);

#pragma unroll
    for (int g = 0; g < 4; ++g) {  // 4 groups of 8 k-steps (k-step = 16)
        const int cur = g & 1, nxt = cur ^ 1;
        if (g < 3) {
#pragma unroll
            for (int ks = 0; ks < 8; ++ks)
                a[nxt][ks] = *(const short8*)(arow + (g + 1) * 128 + ks * 16);
        }
#pragma unroll
        for (int ks = 0; ks < 8; ++ks) {
            const int kg = g * 8 + ks;
            short8 w0 = *(const short8*)&lsW[(size_t)kg * 512 + lane * 8];         // nb=0
            short8 w1 = *(const short8*)&lsW[(size_t)(32 + kg) * 512 + lane * 8];  // nb=1
            acc0 = __builtin_amdgcn_mfma_f32_32x32x16_bf16(a[cur][ks], w0, acc0, 0, 0, 0);
            acc1 = __builtin_amdgcn_mfma_f32_32x32x16_bf16(a[cur][ks], w1, acc1, 0, 0, 0);
        }
    }

    // epilogue: 32x32 C/D map col=lane&31, row=(reg&3)+8*(reg>>2)+4*(lane>>5)
#pragma unroll
    for (int nb = 0; nb < 2; ++nb) {
        const floatx16 acc = nb ? acc1 : acc0;
        const int col = tileN + nb * 32 + l31;
        const float bv = has_bias_relu ? bias[col] : 0.f;
#pragma unroll
        for (int reg = 0; reg < 16; ++reg) {
            const int row = m0 + (reg & 3) + 8 * (reg >> 2) + 4 * khalf;
            if (row < M) {
                float v = acc[reg];
                if (has_bias_relu) { v += bv; v = fmaxf(v, 0.f); }
                C[(size_t)row * 512 + col] = f2bf(v);
            }
        }
    }
}

// ---------- SpMM + bias + relu: one wave/row, 16B/lane gathers, 8-deep unroll ----------
__global__ __launch_bounds__(256)
void spmm_bias_relu(const int* __restrict__ row_ptr, const int* __restrict__ cols,
                    const float* __restrict__ vals, const unsigned short* __restrict__ hmat,
                    const float* __restrict__ bias, unsigned short* __restrict__ xout) {
    const int wave = threadIdx.x >> 6, lane = threadIdx.x & 63;
    const int r = blockIdx.x * 4 + wave;
    if (r >= NNODES) return;
    const int s = row_ptr[r], e = row_ptr[r + 1];
    const int cb = lane * 8;
    float acc[8] = {0.f, 0.f, 0.f, 0.f, 0.f, 0.f, 0.f, 0.f};

    int i = s;
    for (; i + 8 <= e; i += 8) {
        int c[8]; float v[8]; short8 g[8];
#pragma unroll
        for (int u = 0; u < 8; ++u) { c[u] = cols[i + u]; v[u] = vals[i + u]; }
#pragma unroll
        for (int u = 0; u < 8; ++u) g[u] = *(const short8*)(hmat + (size_t)c[u] * H + cb);
#pragma unroll
        for (int u = 0; u < 8; ++u)  // edge order preserved per column
#pragma unroll
            for (int j = 0; j < 8; ++j) acc[j] += v[u] * bf2f((unsigned short)g[u][j]);
    }
    for (; i + 2 <= e; i += 2) {
        const int c0 = cols[i], c1 = cols[i + 1];
        const float v0 = vals[i], v1 = vals[i + 1];
        short8 g0 = *(const short8*)(hmat + (size_t)c0 * H + cb);
        short8 g1 = *(const short8*)(hmat + (size_t)c1 * H + cb);
#pragma unroll
        for (int j = 0; j < 8; ++j) { acc[j] += v0 * bf2f((unsigned short)g0[j]); }
#pragma unroll
        for (int j = 0; j < 8; ++j) { acc[j] += v1 * bf2f((unsigned short)g1[j]); }
    }
    if (i < e) {
        const int c = cols[i];
        const float v = vals[i];
        short8 g = *(const short8*)(hmat + (size_t)c * H + cb);
#pragma unroll
        for (int j = 0; j < 8; ++j) acc[j] += v * bf2f((unsigned short)g[j]);
    }

    short8 o;
#pragma unroll
    for (int j = 0; j < 8; ++j)
        o[j] = (short)f2bf(fmaxf(acc[j] + bias[cb + j], 0.f));
    *(short8*)(xout + (size_t)r * H + cb) = o;
}

// ---------- head: out[r] = sigmoid(dot(h2[r,:], w2) + b2) ----------
__global__ __launch_bounds__(256)
void final_head(const unsigned short* __restrict__ h2, const float* __restrict__ w2,
                const float* __restrict__ b2, float* __restrict__ out, int n) {
    const int wave = threadIdx.x >> 6, lane = threadIdx.x & 63;
    const int r = blockIdx.x * 4 + wave;
    if (r >= n) return;
    const unsigned short* hrow = h2 + (size_t)r * H;
    float acc = 0.f;
#pragma unroll
    for (int i = 0; i < 8; ++i) {
        const int c = lane * 8 + i;
        acc += bf2f(hrow[c]) * w2[c];
    }
#pragma unroll
    for (int off = 32; off >= 1; off >>= 1) acc += __shfl_xor(acc, off, 64);
    if (lane == 0) out[r] = 1.f / (1.f + expf(-(acc + b2[0])));
}

extern "C" void kernel_launch(void* const* d_in, const int* in_sizes, int n_in,
                              void* d_out, int out_size, void* d_ws, size_t ws_size,
                              hipStream_t stream) {
    (void)in_sizes; (void)n_in; (void)out_size; (void)ws_size;
    const float* feat   = (const float*)d_in[0];
    const int* adj_row  = (const int*)d_in[1];
    const int* adj_col  = (const int*)d_in[2];
    const float* adj_val= (const float*)d_in[3];
    const float* Wg     = (const float*)d_in[4];
    const float* bg     = (const float*)d_in[5];
    const float* vw1    = (const float*)d_in[6];
    const float* vb1    = (const float*)d_in[7];
    const float* vw2    = (const float*)d_in[8];
    const float* vb2    = (const float*)d_in[9];
    float* out = (float*)d_out;

    // workspace layout (bytes)
    char* ws = (char*)d_ws;
    unsigned short* x  = (unsigned short*)(ws + 0);          // 10,240,000
    unsigned short* h  = (unsigned short*)(ws + 10240000);   // 10,240,000
    unsigned short* Wt = (unsigned short*)(ws + 20480000);   // 3,145,728
    int*   row_ptr = (int*)(ws + 23625728);                  // 40,960
    int*   counts  = (int*)(ws + 23666688);                  // 40,960
    int*   fill    = (int*)(ws + 23707648);                  // 40,960
    int*   colsS   = (int*)(ws + 23748608);                  // 640,000
    float* valsS   = (float*)(ws + 24388608);                // 640,000
    int*   eidxS   = (int*)(ws + 25028608);                  // 640,000 -> ~25.7 MB

    // --- prep ---
    zero_int<<<(20480 + 255) / 256, 256, 0, stream>>>(counts, 20480);  // counts + fill
    cvt_f32_bf16<<<(NNODES * H / 4 + 255) / 256, 256, 0, stream>>>(feat, x, NNODES * H / 4);
    transpose_cvt6<<<dim3(16, 16, 6), dim3(32, 8), 0, stream>>>(Wg, vw1, Wt);
    edge_hist<<<(NEDGES + 255) / 256, 256, 0, stream>>>(adj_row, counts, NEDGES);
    scan_rows<<<1, 1024, 0, stream>>>(counts, row_ptr, NNODES);
    edge_scatter<<<(NEDGES + 255) / 256, 256, 0, stream>>>(adj_row, adj_col, adj_val,
                                                           row_ptr, fill, colsS, valsS, eidxS, NEDGES);
    sort_rows<<<(NNODES + 3) / 4, 256, 0, stream>>>(row_ptr, colsS, valsS, eidxS);

    // --- layers ---
    dim3 gg((NNODES + 127) / 128, 8);  // (79, 8)
    for (int l = 0; l < NLAYERS; ++l) {
        gemm_ws<<<gg, 256, 0, stream>>>(x, Wt + (size_t)l * H * H, h, nullptr, 0, NNODES);
        spmm_bias_relu<<<(NNODES + 3) / 4, 256, 0, stream>>>(row_ptr, colsS, valsS, h, bg + (size_t)l * H, x);
    }
    gemm_ws<<<gg, 256, 0, stream>>>(x, Wt + (size_t)NLAYERS * H * H, h, vb1, 1, NNODES);
    final_head<<<(NNODES + 3) / 4, 256, 0, stream>>>(h, vw2, vb2, out, NNODES);
}

// Round 5
// 440.583 us; speedup vs baseline: 1.0545x; 1.0545x over previous
//
#include <hip/hip_runtime.h>

#define H 512
#define NNODES 10000
#define NEDGES 160000
#define NLAYERS 5

typedef __attribute__((ext_vector_type(8))) short short8;
typedef __attribute__((ext_vector_type(4))) float floatx4;

// ---------- helpers ----------
__device__ inline unsigned short f2bf(float v) {
    union { float f; unsigned int u; } x; x.f = v;
    unsigned int r = (x.u + 0x7fffu + ((x.u >> 16) & 1u)) >> 16;
    return (unsigned short)r;
}
__device__ inline float bf2f(unsigned short u) {
    union { unsigned int u; float f; } x; x.u = ((unsigned int)u) << 16; return x.f;
}
__device__ inline void gl_lds16(const void* g, void* l) {
    __builtin_amdgcn_global_load_lds((const __attribute__((address_space(1))) void*)g,
                                     (__attribute__((address_space(3))) void*)l, 16, 0, 0);
}

// ---------- prep kernels ----------
__global__ void zero_int(int* __restrict__ p, int n) {
    int i = blockIdx.x * blockDim.x + threadIdx.x;
    if (i < n) p[i] = 0;
}

__global__ void cvt_f32_bf16(const float* __restrict__ in, unsigned short* __restrict__ out, int n4) {
    int i = blockIdx.x * blockDim.x + threadIdx.x;
    if (i < n4) {
        float4 v = ((const float4*)in)[i];
        ushort4 o;
        o.x = f2bf(v.x); o.y = f2bf(v.y); o.z = f2bf(v.z); o.w = f2bf(v.w);
        ((ushort4*)out)[i] = o;
    }
}

// batched: z in [0,6): 5 layer weights + vw1. out[n][k] = in[k][n], bf16
__global__ void transpose_cvt6(const float* __restrict__ Wg, const float* __restrict__ vw1,
                               unsigned short* __restrict__ Wt) {
    __shared__ float tile[32][33];
    const int z = blockIdx.z;
    const float* in = (z < NLAYERS) ? (Wg + (size_t)z * H * H) : vw1;
    unsigned short* out = Wt + (size_t)z * H * H;
    const int bx = blockIdx.x * 32;  // n base
    const int by = blockIdx.y * 32;  // k base
    const int tx = threadIdx.x, ty = threadIdx.y;  // (32,8)
    for (int i = ty; i < 32; i += 8)
        tile[i][tx] = in[(size_t)(by + i) * H + bx + tx];
    __syncthreads();
    for (int i = ty; i < 32; i += 8)
        out[(size_t)(bx + i) * H + by + tx] = f2bf(tile[tx][i]);
}

__global__ void edge_hist(const int* __restrict__ rows, int* __restrict__ counts, int n) {
    int i = blockIdx.x * blockDim.x + threadIdx.x;
    if (i < n) atomicAdd(&counts[rows[i]], 1);
}

__global__ __launch_bounds__(1024)
void scan_rows(const int* __restrict__ counts, int* __restrict__ row_ptr, int n) {
    __shared__ int sums[1024];
    const int t = threadIdx.x;
    const int base = t * 16;
    int local[16];
    int s = 0;
#pragma unroll
    for (int i = 0; i < 16; ++i) {
        int idx = base + i;
        int v = (idx < n) ? counts[idx] : 0;
        local[i] = s;
        s += v;
    }
    sums[t] = s;
    __syncthreads();
    for (int off = 1; off < 1024; off <<= 1) {
        int v = (t >= off) ? sums[t - off] : 0;
        __syncthreads();
        sums[t] += v;
        __syncthreads();
    }
    const int prefix = (t == 0) ? 0 : sums[t - 1];
#pragma unroll
    for (int i = 0; i < 16; ++i) {
        int idx = base + i;
        if (idx < n) row_ptr[idx] = prefix + local[i];
    }
    if (t == 0) row_ptr[n] = sums[1023];
}

__global__ void edge_scatter(const int* __restrict__ rows, const int* __restrict__ colsin,
                             const float* __restrict__ valsin, const int* __restrict__ row_ptr,
                             int* __restrict__ fill, int* __restrict__ colsout,
                             float* __restrict__ valsout, int* __restrict__ eidx, int n) {
    int i = blockIdx.x * blockDim.x + threadIdx.x;
    if (i < n) {
        int r = rows[i];
        int pos = row_ptr[r] + atomicAdd(&fill[r], 1);
        colsout[pos] = colsin[i];
        valsout[pos] = valsin[i];
        eidx[pos] = i;
    }
}

// per-row odd-even transposition sort by original edge index -> accumulation
// order matches reference segment_sum exactly (deterministic absmax).
__global__ __launch_bounds__(256)
void sort_rows(const int* __restrict__ row_ptr, int* __restrict__ cols,
               float* __restrict__ vals, const int* __restrict__ eidx) {
    const int wave = threadIdx.x >> 6, lane = threadIdx.x & 63;
    const int r = blockIdx.x * 4 + wave;
    if (r >= NNODES) return;
    const int s = row_ptr[r], e = row_ptr[r + 1];
    const int len = e - s;
    if (len <= 1) return;
    const int n = len < 64 ? len : 64;
    int key = (lane < n) ? eidx[s + lane] : 0x7fffffff;
    int col = (lane < n) ? cols[s + lane] : 0;
    float val = (lane < n) ? vals[s + lane] : 0.f;
    for (int rd = 0; rd < 64; ++rd) {
        const int p = rd & 1;
        const bool up = ((lane & 1) == p);
        int partner = up ? lane + 1 : lane - 1;
        const bool valid = (partner >= 0) && (partner < 64);
        if (!valid) partner = lane;
        int pk = __shfl(key, partner, 64);
        int pc = __shfl(col, partner, 64);
        float pv = __shfl(val, partner, 64);
        if (valid) {
            const bool sw = up ? (pk < key) : (pk > key);
            if (sw) { key = pk; col = pc; val = pv; }
        }
    }
    if (lane < n) { cols[s + lane] = col; vals[s + lane] = val; }
}

// ---------- GEMM v3: C[M,512] = A[M,512] * Bt[512,512]^T (bf16 in, bf16 out) ----------
// LDS-BW-aware design: A frags stream global->VGPR (no LDS); B frags staged
// fragment-major into double-buffered LDS (ds_read_b128 lane-consecutive,
// conflict-free). Tile 128x128, BK=64, 8 iters, grid (79,4)=316 blocks.
// Per wave-iter: 8 a-gathers + 8 KB LDS reads feed 32 MFMAs (16x16x32).
__global__ __launch_bounds__(256)
void gemm_bf16_v3(const unsigned short* __restrict__ A, const unsigned short* __restrict__ Bt,
                  unsigned short* __restrict__ C, const float* __restrict__ bias,
                  int has_bias_relu, int M) {
    // [buf 2][frag 16][lane 64][elem 8] : frag f = kk*8 + j ; 32 KB total
    __shared__ __align__(16) unsigned short lsB[2 * 16 * 512];
    const int t = threadIdx.x;
    const int lane = t & 63;
    const int wave = t >> 6;
    const int wm = wave >> 1, wn = wave & 1;
    const int tileM = blockIdx.x * 128;
    const int tileN = blockIdx.y * 128;
    const int quad = lane >> 4, r16 = lane & 15;

    // B staging: 16 frags/iter, wave stages frags f = wave*4 + q.
    // frag f (kk=f>>3, j=f&7): lane holds Bt[tileN + j*16 + r16][k0 + kk*32 + quad*8 ..+8]
    const unsigned short* bsrc[4];
#pragma unroll
    for (int q = 0; q < 4; ++q) {
        const int f = wave * 4 + q;
        bsrc[q] = Bt + (size_t)(tileN + (f & 7) * 16 + r16) * 512 + (f >> 3) * 32 + quad * 8;
    }
    // A frag sources (direct global->VGPR): frag i: lane holds
    // A[tileM + wm*64 + i*16 + r16][k0 + kk*32 + quad*8 ..+8]
    const unsigned short* asrc[4];
#pragma unroll
    for (int i = 0; i < 4; ++i) {
        int row = tileM + wm * 64 + i * 16 + r16;
        if (row >= M) row = M - 1;
        asrc[i] = A + (size_t)row * 512 + quad * 8;
    }

    // prologue: stage buf0 (k0 = 0)
#pragma unroll
    for (int q = 0; q < 4; ++q)
        gl_lds16(bsrc[q], lsB + (size_t)(wave * 4 + q) * 512 + lane * 8);
    __syncthreads();

    floatx4 acc[4][4] = {};

    for (int it = 0; it < 8; ++it) {
        const int cur = it & 1, nxt = cur ^ 1;
        const int k0 = it * 64;
        if (it < 7) {
#pragma unroll
            for (int q = 0; q < 4; ++q)
                gl_lds16(bsrc[q] + k0 + 64,
                         lsB + (size_t)(nxt * 16 + wave * 4 + q) * 512 + lane * 8);
        }
        // A frags: 8 independent 16B gathers (L1 reuses each 128B line across kk)
        short8 a[4][2];
#pragma unroll
        for (int i = 0; i < 4; ++i)
#pragma unroll
            for (int kk = 0; kk < 2; ++kk)
                a[i][kk] = *(const short8*)(asrc[i] + k0 + kk * 32);
        // B frags: conflict-free lane-consecutive ds_read_b128
        short8 b[4][2];
#pragma unroll
        for (int j = 0; j < 4; ++j)
#pragma unroll
            for (int kk = 0; kk < 2; ++kk)
                b[j][kk] = *(const short8*)&lsB[(size_t)(cur * 16 + kk * 8 + wn * 4 + j) * 512 + lane * 8];
#pragma unroll
        for (int kk = 0; kk < 2; ++kk)  // K ascending -> numerics match prior rounds
#pragma unroll
            for (int i = 0; i < 4; ++i)
#pragma unroll
                for (int j = 0; j < 4; ++j)
                    acc[i][j] = __builtin_amdgcn_mfma_f32_16x16x32_bf16(a[i][kk], b[j][kk], acc[i][j], 0, 0, 0);
        __syncthreads();
    }

    // epilogue: C/D map col=lane&15, row=(lane>>4)*4+reg
#pragma unroll
    for (int i = 0; i < 4; ++i) {
#pragma unroll
        for (int j = 0; j < 4; ++j) {
            const int col = tileN + wn * 64 + j * 16 + r16;
#pragma unroll
            for (int reg = 0; reg < 4; ++reg) {
                const int row = tileM + wm * 64 + i * 16 + quad * 4 + reg;
                if (row < M) {
                    float v = acc[i][j][reg];
                    if (has_bias_relu) { v += bias[col]; v = fmaxf(v, 0.f); }
                    C[(size_t)row * 512 + col] = f2bf(v);
                }
            }
        }
    }
}

// ---------- SpMM + bias + relu: one wave/row, 16B/lane gathers, 8-deep unroll ----------
__global__ __launch_bounds__(256)
void spmm_bias_relu(const int* __restrict__ row_ptr, const int* __restrict__ cols,
                    const float* __restrict__ vals, const unsigned short* __restrict__ hmat,
                    const float* __restrict__ bias, unsigned short* __restrict__ xout) {
    const int wave = threadIdx.x >> 6, lane = threadIdx.x & 63;
    const int r = blockIdx.x * 4 + wave;
    if (r >= NNODES) return;
    const int s = row_ptr[r], e = row_ptr[r + 1];
    const int cb = lane * 8;
    float acc[8] = {0.f, 0.f, 0.f, 0.f, 0.f, 0.f, 0.f, 0.f};

    int i = s;
    for (; i + 8 <= e; i += 8) {
        int c[8]; float v[8]; short8 g[8];
#pragma unroll
        for (int u = 0; u < 8; ++u) { c[u] = cols[i + u]; v[u] = vals[i + u]; }
#pragma unroll
        for (int u = 0; u < 8; ++u) g[u] = *(const short8*)(hmat + (size_t)c[u] * H + cb);
#pragma unroll
        for (int u = 0; u < 8; ++u)  // edge order preserved per column
#pragma unroll
            for (int j = 0; j < 8; ++j) acc[j] += v[u] * bf2f((unsigned short)g[u][j]);
    }
    for (; i + 2 <= e; i += 2) {
        const int c0 = cols[i], c1 = cols[i + 1];
        const float v0 = vals[i], v1 = vals[i + 1];
        short8 g0 = *(const short8*)(hmat + (size_t)c0 * H + cb);
        short8 g1 = *(const short8*)(hmat + (size_t)c1 * H + cb);
#pragma unroll
        for (int j = 0; j < 8; ++j) { acc[j] += v0 * bf2f((unsigned short)g0[j]); }
#pragma unroll
        for (int j = 0; j < 8; ++j) { acc[j] += v1 * bf2f((unsigned short)g1[j]); }
    }
    if (i < e) {
        const int c = cols[i];
        const float v = vals[i];
        short8 g = *(const short8*)(hmat + (size_t)c * H + cb);
#pragma unroll
        for (int j = 0; j < 8; ++j) acc[j] += v * bf2f((unsigned short)g[j]);
    }

    short8 o;
#pragma unroll
    for (int j = 0; j < 8; ++j)
        o[j] = (short)f2bf(fmaxf(acc[j] + bias[cb + j], 0.f));
    *(short8*)(xout + (size_t)r * H + cb) = o;
}

// ---------- head: out[r] = sigmoid(dot(h2[r,:], w2) + b2) ----------
__global__ __launch_bounds__(256)
void final_head(const unsigned short* __restrict__ h2, const float* __restrict__ w2,
                const float* __restrict__ b2, float* __restrict__ out, int n) {
    const int wave = threadIdx.x >> 6, lane = threadIdx.x & 63;
    const int r = blockIdx.x * 4 + wave;
    if (r >= n) return;
    const unsigned short* hrow = h2 + (size_t)r * H;
    float acc = 0.f;
#pragma unroll
    for (int i = 0; i < 8; ++i) {
        const int c = lane * 8 + i;
        acc += bf2f(hrow[c]) * w2[c];
    }
#pragma unroll
    for (int off = 32; off >= 1; off >>= 1) acc += __shfl_xor(acc, off, 64);
    if (lane == 0) out[r] = 1.f / (1.f + expf(-(acc + b2[0])));
}

extern "C" void kernel_launch(void* const* d_in, const int* in_sizes, int n_in,
                              void* d_out, int out_size, void* d_ws, size_t ws_size,
                              hipStream_t stream) {
    (void)in_sizes; (void)n_in; (void)out_size; (void)ws_size;
    const float* feat   = (const float*)d_in[0];
    const int* adj_row  = (const int*)d_in[1];
    const int* adj_col  = (const int*)d_in[2];
    const float* adj_val= (const float*)d_in[3];
    const float* Wg     = (const float*)d_in[4];
    const float* bg     = (const float*)d_in[5];
    const float* vw1    = (const float*)d_in[6];
    const float* vb1    = (const float*)d_in[7];
    const float* vw2    = (const float*)d_in[8];
    const float* vb2    = (const float*)d_in[9];
    float* out = (float*)d_out;

    // workspace layout (bytes)
    char* ws = (char*)d_ws;
    unsigned short* x  = (unsigned short*)(ws + 0);          // 10,240,000
    unsigned short* h  = (unsigned short*)(ws + 10240000);   // 10,240,000
    unsigned short* Wt = (unsigned short*)(ws + 20480000);   // 3,145,728
    int*   row_ptr = (int*)(ws + 23625728);                  // 40,960
    int*   counts  = (int*)(ws + 23666688);                  // 40,960
    int*   fill    = (int*)(ws + 23707648);                  // 40,960
    int*   colsS   = (int*)(ws + 23748608);                  // 640,000
    float* valsS   = (float*)(ws + 24388608);                // 640,000
    int*   eidxS   = (int*)(ws + 25028608);                  // 640,000 -> ~25.7 MB

    // --- prep ---
    zero_int<<<(20480 + 255) / 256, 256, 0, stream>>>(counts, 20480);  // counts + fill
    cvt_f32_bf16<<<(NNODES * H / 4 + 255) / 256, 256, 0, stream>>>(feat, x, NNODES * H / 4);
    transpose_cvt6<<<dim3(16, 16, 6), dim3(32, 8), 0, stream>>>(Wg, vw1, Wt);
    edge_hist<<<(NEDGES + 255) / 256, 256, 0, stream>>>(adj_row, counts, NEDGES);
    scan_rows<<<1, 1024, 0, stream>>>(counts, row_ptr, NNODES);
    edge_scatter<<<(NEDGES + 255) / 256, 256, 0, stream>>>(adj_row, adj_col, adj_val,
                                                           row_ptr, fill, colsS, valsS, eidxS, NEDGES);
    sort_rows<<<(NNODES + 3) / 4, 256, 0, stream>>>(row_ptr, colsS, valsS, eidxS);

    // --- layers ---
    dim3 gg((NNODES + 127) / 128, 4);  // (79, 4) = 316 blocks
    for (int l = 0; l < NLAYERS; ++l) {
        gemm_bf16_v3<<<gg, 256, 0, stream>>>(x, Wt + (size_t)l * H * H, h, nullptr, 0, NNODES);
        spmm_bias_relu<<<(NNODES + 3) / 4, 256, 0, stream>>>(row_ptr, colsS, valsS, h, bg + (size_t)l * H, x);
    }
    gemm_bf16_v3<<<gg, 256, 0, stream>>>(x, Wt + (size_t)NLAYERS * H * H, h, vb1, 1, NNODES);
    final_head<<<(NNODES + 3) / 4, 256, 0, stream>>>(h, vw2, vb2, out, NNODES);
}

// Round 6
// 405.748 us; speedup vs baseline: 1.1451x; 1.0859x over previous
//
#include <hip/hip_runtime.h>

#define H 512
#define NNODES 10000
#define NEDGES 160000
#define NLAYERS 5

typedef __attribute__((ext_vector_type(8))) short short8;
typedef __attribute__((ext_vector_type(4))) float floatx4;

// ---------- helpers ----------
__device__ inline unsigned short f2bf(float v) {
    union { float f; unsigned int u; } x; x.f = v;
    unsigned int r = (x.u + 0x7fffu + ((x.u >> 16) & 1u)) >> 16;
    return (unsigned short)r;
}
__device__ inline float bf2f(unsigned short u) {
    union { unsigned int u; float f; } x; x.u = ((unsigned int)u) << 16; return x.f;
}
__device__ inline void gl_lds16(const void* g, void* l) {
    __builtin_amdgcn_global_load_lds((const __attribute__((address_space(1))) void*)g,
                                     (__attribute__((address_space(3))) void*)l, 16, 0, 0);
}

// ---------- prep kernels ----------
__global__ void zero_int(int* __restrict__ p, int n) {
    int i = blockIdx.x * blockDim.x + threadIdx.x;
    if (i < n) p[i] = 0;
}

__global__ void cvt_f32_bf16(const float* __restrict__ in, unsigned short* __restrict__ out, int n4) {
    int i = blockIdx.x * blockDim.x + threadIdx.x;
    if (i < n4) {
        float4 v = ((const float4*)in)[i];
        ushort4 o;
        o.x = f2bf(v.x); o.y = f2bf(v.y); o.z = f2bf(v.z); o.w = f2bf(v.w);
        ((ushort4*)out)[i] = o;
    }
}

// batched: z in [0,6): 5 layer weights + vw1. out[n][k] = in[k][n], bf16
__global__ void transpose_cvt6(const float* __restrict__ Wg, const float* __restrict__ vw1,
                               unsigned short* __restrict__ Wt) {
    __shared__ float tile[32][33];
    const int z = blockIdx.z;
    const float* in = (z < NLAYERS) ? (Wg + (size_t)z * H * H) : vw1;
    unsigned short* out = Wt + (size_t)z * H * H;
    const int bx = blockIdx.x * 32;  // n base
    const int by = blockIdx.y * 32;  // k base
    const int tx = threadIdx.x, ty = threadIdx.y;  // (32,8)
    for (int i = ty; i < 32; i += 8)
        tile[i][tx] = in[(size_t)(by + i) * H + bx + tx];
    __syncthreads();
    for (int i = ty; i < 32; i += 8)
        out[(size_t)(bx + i) * H + by + tx] = f2bf(tile[tx][i]);
}

__global__ void edge_hist(const int* __restrict__ rows, int* __restrict__ counts, int n) {
    int i = blockIdx.x * blockDim.x + threadIdx.x;
    if (i < n) atomicAdd(&counts[rows[i]], 1);
}

__global__ __launch_bounds__(1024)
void scan_rows(const int* __restrict__ counts, int* __restrict__ row_ptr, int n) {
    __shared__ int sums[1024];
    const int t = threadIdx.x;
    const int base = t * 16;
    int local[16];
    int s = 0;
#pragma unroll
    for (int i = 0; i < 16; ++i) {
        int idx = base + i;
        int v = (idx < n) ? counts[idx] : 0;
        local[i] = s;
        s += v;
    }
    sums[t] = s;
    __syncthreads();
    for (int off = 1; off < 1024; off <<= 1) {
        int v = (t >= off) ? sums[t - off] : 0;
        __syncthreads();
        sums[t] += v;
        __syncthreads();
    }
    const int prefix = (t == 0) ? 0 : sums[t - 1];
#pragma unroll
    for (int i = 0; i < 16; ++i) {
        int idx = base + i;
        if (idx < n) row_ptr[idx] = prefix + local[i];
    }
    if (t == 0) row_ptr[n] = sums[1023];
}

__global__ void edge_scatter(const int* __restrict__ rows, const int* __restrict__ colsin,
                             const float* __restrict__ valsin, const int* __restrict__ row_ptr,
                             int* __restrict__ fill, int* __restrict__ colsout,
                             float* __restrict__ valsout, int* __restrict__ eidx, int n) {
    int i = blockIdx.x * blockDim.x + threadIdx.x;
    if (i < n) {
        int r = rows[i];
        int pos = row_ptr[r] + atomicAdd(&fill[r], 1);
        colsout[pos] = colsin[i];
        valsout[pos] = valsin[i];
        eidx[pos] = i;
    }
}

// per-row odd-even transposition sort by original edge index -> accumulation
// order matches reference segment_sum exactly (deterministic absmax).
__global__ __launch_bounds__(256)
void sort_rows(const int* __restrict__ row_ptr, int* __restrict__ cols,
               float* __restrict__ vals, const int* __restrict__ eidx) {
    const int wave = threadIdx.x >> 6, lane = threadIdx.x & 63;
    const int r = blockIdx.x * 4 + wave;
    if (r >= NNODES) return;
    const int s = row_ptr[r], e = row_ptr[r + 1];
    const int len = e - s;
    if (len <= 1) return;
    const int n = len < 64 ? len : 64;
    int key = (lane < n) ? eidx[s + lane] : 0x7fffffff;
    int col = (lane < n) ? cols[s + lane] : 0;
    float val = (lane < n) ? vals[s + lane] : 0.f;
    for (int rd = 0; rd < 64; ++rd) {
        const int p = rd & 1;
        const bool up = ((lane & 1) == p);
        int partner = up ? lane + 1 : lane - 1;
        const bool valid = (partner >= 0) && (partner < 64);
        if (!valid) partner = lane;
        int pk = __shfl(key, partner, 64);
        int pc = __shfl(col, partner, 64);
        float pv = __shfl(val, partner, 64);
        if (valid) {
            const bool sw = up ? (pk < key) : (pk > key);
            if (sw) { key = pk; col = pc; val = pv; }
        }
    }
    if (lane < n) { cols[s + lane] = col; vals[s + lane] = val; }
}

// ---------- GEMM v4: 64x64 tile, max TLP. C[M,512] = A[M,512]*Bt[512,512]^T ----------
// Grid (157,8)=1256 blocks (~4.9/CU co-resident; 32KB LDS -> 5 blocks/CU cap).
// Coalesced gl_lds staging (r2/r3-proven; r4/r5 showed per-lane gathers lose).
// Double-buffered, ONE barrier/iter: stage-next issued AFTER the barrier so the
// next barrier's vmcnt(0) drain waits on loads a full compute-phase old.
// XOR k-slot swizzle: frag ds_read_b128 spreads 8 lanes/bank (structural min).
__global__ __launch_bounds__(256)
void gemm_bf16_64(const unsigned short* __restrict__ A, const unsigned short* __restrict__ Bt,
                  unsigned short* __restrict__ C, const float* __restrict__ bias,
                  int has_bias_relu, int M) {
    __shared__ __align__(16) unsigned short lsA[2 * 4096];  // 2 x 64x64 bf16 = 16 KB
    __shared__ __align__(16) unsigned short lsB[2 * 4096];  // 16 KB
    const int t = threadIdx.x;
    const int lane = t & 63;
    const int wave = t >> 6;          // 0..3 = N-quarter
    const int quad = lane >> 4, r16 = lane & 15;
    const int tileM = blockIdx.x * 64;
    const int tileN = blockIdx.y * 64;

    // staging sources: chunk c = t, t+256; row = c>>3, slot = c&7,
    // global k-offset = (slot ^ (row&7))*8  (permuted within the 128B row -> coalesced)
    const unsigned short* aS[2];
    const unsigned short* bS[2];
    int ldst[2];
#pragma unroll
    for (int q = 0; q < 2; ++q) {
        const int c = t + 256 * q;
        const int row = c >> 3, slot = c & 7;
        int gr = tileM + row; if (gr >= M) gr = M - 1;
        aS[q] = A + (size_t)gr * 512 + ((slot ^ (row & 7)) * 8);
        bS[q] = Bt + (size_t)(tileN + row) * 512 + ((slot ^ (row & 7)) * 8);
        ldst[q] = c * 8;  // elems
    }

    // prologue: stage buf0 (k0 = 0)
#pragma unroll
    for (int q = 0; q < 2; ++q) {
        gl_lds16(aS[q], lsA + ldst[q]);
        gl_lds16(bS[q], lsB + ldst[q]);
    }

    floatx4 acc[4] = {};

    for (int it = 0; it < 8; ++it) {
        const int cur = it & 1;
        __syncthreads();  // drains staging issued one compute-phase ago
        if (it < 7) {
            const int nxt = cur ^ 1;
            const int k1 = (it + 1) * 64;
#pragma unroll
            for (int q = 0; q < 2; ++q) {
                gl_lds16(aS[q] + k1, lsA + nxt * 4096 + ldst[q]);
                gl_lds16(bS[q] + k1, lsB + nxt * 4096 + ldst[q]);
            }
        }
        short8 a[4][2], b[2];
#pragma unroll
        for (int kk = 0; kk < 2; ++kk) {
            const int sw = ((kk * 4 + quad) ^ (r16 & 7)) * 8;
            b[kk] = *(const short8*)&lsB[cur * 4096 + (wave * 16 + r16) * 64 + sw];
#pragma unroll
            for (int i = 0; i < 4; ++i)
                a[i][kk] = *(const short8*)&lsA[cur * 4096 + (i * 16 + r16) * 64 + sw];
        }
#pragma unroll
        for (int kk = 0; kk < 2; ++kk)  // K ascending -> numerics identical to r3
#pragma unroll
            for (int i = 0; i < 4; ++i)
                acc[i] = __builtin_amdgcn_mfma_f32_16x16x32_bf16(a[i][kk], b[kk], acc[i], 0, 0, 0);
    }

    // epilogue: C/D map col=lane&15, row=(lane>>4)*4+reg
    const int col = tileN + wave * 16 + r16;
    const float bv = has_bias_relu ? bias[col] : 0.f;
#pragma unroll
    for (int i = 0; i < 4; ++i) {
#pragma unroll
        for (int reg = 0; reg < 4; ++reg) {
            const int row = tileM + i * 16 + quad * 4 + reg;
            if (row < M) {
                float v = acc[i][reg];
                if (has_bias_relu) { v += bv; v = fmaxf(v, 0.f); }
                C[(size_t)row * 512 + col] = f2bf(v);
            }
        }
    }
}

// ---------- SpMM + bias + relu: one wave/row, 16B/lane gathers, 8-deep unroll ----------
__global__ __launch_bounds__(256)
void spmm_bias_relu(const int* __restrict__ row_ptr, const int* __restrict__ cols,
                    const float* __restrict__ vals, const unsigned short* __restrict__ hmat,
                    const float* __restrict__ bias, unsigned short* __restrict__ xout) {
    const int wave = threadIdx.x >> 6, lane = threadIdx.x & 63;
    const int r = blockIdx.x * 4 + wave;
    if (r >= NNODES) return;
    const int s = row_ptr[r], e = row_ptr[r + 1];
    const int cb = lane * 8;
    float acc[8] = {0.f, 0.f, 0.f, 0.f, 0.f, 0.f, 0.f, 0.f};

    int i = s;
    for (; i + 8 <= e; i += 8) {
        int c[8]; float v[8]; short8 g[8];
#pragma unroll
        for (int u = 0; u < 8; ++u) { c[u] = cols[i + u]; v[u] = vals[i + u]; }
#pragma unroll
        for (int u = 0; u < 8; ++u) g[u] = *(const short8*)(hmat + (size_t)c[u] * H + cb);
#pragma unroll
        for (int u = 0; u < 8; ++u)  // edge order preserved per column
#pragma unroll
            for (int j = 0; j < 8; ++j) acc[j] += v[u] * bf2f((unsigned short)g[u][j]);
    }
    for (; i + 2 <= e; i += 2) {
        const int c0 = cols[i], c1 = cols[i + 1];
        const float v0 = vals[i], v1 = vals[i + 1];
        short8 g0 = *(const short8*)(hmat + (size_t)c0 * H + cb);
        short8 g1 = *(const short8*)(hmat + (size_t)c1 * H + cb);
#pragma unroll
        for (int j = 0; j < 8; ++j) { acc[j] += v0 * bf2f((unsigned short)g0[j]); }
#pragma unroll
        for (int j = 0; j < 8; ++j) { acc[j] += v1 * bf2f((unsigned short)g1[j]); }
    }
    if (i < e) {
        const int c = cols[i];
        const float v = vals[i];
        short8 g = *(const short8*)(hmat + (size_t)c * H + cb);
#pragma unroll
        for (int j = 0; j < 8; ++j) acc[j] += v * bf2f((unsigned short)g[j]);
    }

    short8 o;
#pragma unroll
    for (int j = 0; j < 8; ++j)
        o[j] = (short)f2bf(fmaxf(acc[j] + bias[cb + j], 0.f));
    *(short8*)(xout + (size_t)r * H + cb) = o;
}

// ---------- head: out[r] = sigmoid(dot(h2[r,:], w2) + b2) ----------
__global__ __launch_bounds__(256)
void final_head(const unsigned short* __restrict__ h2, const float* __restrict__ w2,
                const float* __restrict__ b2, float* __restrict__ out, int n) {
    const int wave = threadIdx.x >> 6, lane = threadIdx.x & 63;
    const int r = blockIdx.x * 4 + wave;
    if (r >= n) return;
    const unsigned short* hrow = h2 + (size_t)r * H;
    float acc = 0.f;
#pragma unroll
    for (int i = 0; i < 8; ++i) {
        const int c = lane * 8 + i;
        acc += bf2f(hrow[c]) * w2[c];
    }
#pragma unroll
    for (int off = 32; off >= 1; off >>= 1) acc += __shfl_xor(acc, off, 64);
    if (lane == 0) out[r] = 1.f / (1.f + expf(-(acc + b2[0])));
}

extern "C" void kernel_launch(void* const* d_in, const int* in_sizes, int n_in,
                              void* d_out, int out_size, void* d_ws, size_t ws_size,
                              hipStream_t stream) {
    (void)in_sizes; (void)n_in; (void)out_size; (void)ws_size;
    const float* feat   = (const float*)d_in[0];
    const int* adj_row  = (const int*)d_in[1];
    const int* adj_col  = (const int*)d_in[2];
    const float* adj_val= (const float*)d_in[3];
    const float* Wg     = (const float*)d_in[4];
    const float* bg     = (const float*)d_in[5];
    const float* vw1    = (const float*)d_in[6];
    const float* vb1    = (const float*)d_in[7];
    const float* vw2    = (const float*)d_in[8];
    const float* vb2    = (const float*)d_in[9];
    float* out = (float*)d_out;

    // workspace layout (bytes)
    char* ws = (char*)d_ws;
    unsigned short* x  = (unsigned short*)(ws + 0);          // 10,240,000
    unsigned short* h  = (unsigned short*)(ws + 10240000);   // 10,240,000
    unsigned short* Wt = (unsigned short*)(ws + 20480000);   // 3,145,728
    int*   row_ptr = (int*)(ws + 23625728);                  // 40,960
    int*   counts  = (int*)(ws + 23666688);                  // 40,960
    int*   fill    = (int*)(ws + 23707648);                  // 40,960
    int*   colsS   = (int*)(ws + 23748608);                  // 640,000
    float* valsS   = (float*)(ws + 24388608);                // 640,000
    int*   eidxS   = (int*)(ws + 25028608);                  // 640,000 -> ~25.7 MB

    // --- prep ---
    zero_int<<<(20480 + 255) / 256, 256, 0, stream>>>(counts, 20480);  // counts + fill
    cvt_f32_bf16<<<(NNODES * H / 4 + 255) / 256, 256, 0, stream>>>(feat, x, NNODES * H / 4);
    transpose_cvt6<<<dim3(16, 16, 6), dim3(32, 8), 0, stream>>>(Wg, vw1, Wt);
    edge_hist<<<(NEDGES + 255) / 256, 256, 0, stream>>>(adj_row, counts, NEDGES);
    scan_rows<<<1, 1024, 0, stream>>>(counts, row_ptr, NNODES);
    edge_scatter<<<(NEDGES + 255) / 256, 256, 0, stream>>>(adj_row, adj_col, adj_val,
                                                           row_ptr, fill, colsS, valsS, eidxS, NEDGES);
    sort_rows<<<(NNODES + 3) / 4, 256, 0, stream>>>(row_ptr, colsS, valsS, eidxS);

    // --- layers ---
    dim3 gg((NNODES + 63) / 64, 8);  // (157, 8) = 1256 blocks
    for (int l = 0; l < NLAYERS; ++l) {
        gemm_bf16_64<<<gg, 256, 0, stream>>>(x, Wt + (size_t)l * H * H, h, nullptr, 0, NNODES);
        spmm_bias_relu<<<(NNODES + 3) / 4, 256, 0, stream>>>(row_ptr, colsS, valsS, h, bg + (size_t)l * H, x);
    }
    gemm_bf16_64<<<gg, 256, 0, stream>>>(x, Wt + (size_t)NLAYERS * H * H, h, vb1, 1, NNODES);
    final_head<<<(NNODES + 3) / 4, 256, 0, stream>>>(h, vw2, vb2, out, NNODES);
}